// Round 8
// baseline (153.333 us; speedup 1.0000x reference)
//
#include <hip/hip_runtime.h>
#include <hip/hip_bf16.h>

#define T_TOK 512
#define H_DIM 2048
#define E_NUM 8
#define I_DIM 1024

typedef __attribute__((ext_vector_type(8))) short short8;
typedef __attribute__((ext_vector_type(4))) float f32x4;

// round-to-nearest-even float -> bf16 (as ushort)
__device__ __forceinline__ unsigned short f2bf(float f) {
    unsigned int u = __float_as_uint(f);
    u += 0x7fff + ((u >> 16) & 1);
    return (unsigned short)(u >> 16);
}

// 8 fp32 -> short8 of bf16 via packed cvt (RNE)
__device__ __forceinline__ short8 cvt8(float4 a, float4 b) {
    union { short8 s; __hip_bfloat162 h[4]; } u;
    u.h[0] = __float22bfloat162_rn(make_float2(a.x, a.y));
    u.h[1] = __float22bfloat162_rn(make_float2(a.z, a.w));
    u.h[2] = __float22bfloat162_rn(make_float2(b.x, b.y));
    u.h[3] = __float22bfloat162_rn(make_float2(b.z, b.w));
    return u.s;
}

// ---------------------------------------------------------------
// Kernel 0: x -> bf16 (1M elems, 8/thread)
// ---------------------------------------------------------------
__global__ __launch_bounds__(256) void xcvt_kernel(
    const float* __restrict__ x, unsigned short* __restrict__ xb)
{
    int i = (blockIdx.x * 256 + threadIdx.x) * 8;
    float4 v0 = *(const float4*)(x + i);
    float4 v1 = *(const float4*)(x + i + 4);
    *(short8*)(xb + i) = cvt8(v0, v1);
}

// ---------------------------------------------------------------
// Kernel 1: routing. 1 block, 512 threads.
// ---------------------------------------------------------------
__global__ __launch_bounds__(512) void routing_kernel(
    const float* __restrict__ logits,
    int* __restrict__ count, int* __restrict__ bucket,
    float* __restrict__ pair_w)
{
    int t = threadIdx.x;
    if (t < E_NUM) count[t] = 0;
    __syncthreads();

    float p[E_NUM];
    float m = -INFINITY;
#pragma unroll
    for (int e = 0; e < E_NUM; ++e) {
        p[e] = logits[t * E_NUM + e];
        m = fmaxf(m, p[e]);
    }
#pragma unroll
    for (int e = 0; e < E_NUM; ++e) p[e] = expf(p[e] - m);
    int i0 = 0;
#pragma unroll
    for (int e = 1; e < E_NUM; ++e) if (p[e] > p[i0]) i0 = e;
    int i1 = (i0 == 0) ? 1 : 0;
#pragma unroll
    for (int e = 0; e < E_NUM; ++e) if (e != i0 && p[e] > p[i1]) i1 = e;
    float denom = p[i0] + p[i1];
    pair_w[2 * t + 0] = p[i0] / denom;
    pair_w[2 * t + 1] = p[i1] / denom;

    int pos0 = atomicAdd(&count[i0], 1);
    bucket[i0 * T_TOK + pos0] = 2 * t + 0;
    int pos1 = atomicAdd(&count[i1], 1);
    bucket[i1 * T_TOK + pos1] = 2 * t + 1;
}

// ---------------------------------------------------------------
// Kernel 2: grouped GEMM1 + SiLU. BM=128, BN=16 gate + 16 up, BK=256.
// Register-staged (T14) with FORCED load concurrency:
//   __launch_bounds__(256,2) -> 256-VGPR cap (room for ~150+ live regs)
//   sched_barrier(0) fences pin: [A-loads][staging loads][MFMA][ds_write]
// so all 24 loads/iter stay in flight (in-order vmcnt: L2-fast A first).
// Double-buffered bf16 LDS, one __syncthreads per K-iter.
// ---------------------------------------------------------------
__global__ __launch_bounds__(256, 2) void gemm1_silu_kernel(
    const unsigned short* __restrict__ xb, const float* __restrict__ w13,
    const int* __restrict__ count, const int* __restrict__ bucket,
    __hip_bfloat16* __restrict__ act)
{
    const int e   = blockIdx.z;
    const int n_e = count[e];
    const int m0  = blockIdx.y * 128;
    if (m0 >= n_e) return;
    const int n0  = blockIdx.x * 16;

    // bf16 tiles: 16 rows x 256 cols (512 B rows), double-buffered
    __shared__ unsigned short sG[2][16 * 256];
    __shared__ unsigned short sU[2][16 * 256];

    const int tid  = threadIdx.x;
    const int lane = tid & 63;
    const int wid  = tid >> 6;     // 0..3
    const int fr   = lane & 15;
    const int fq   = lane >> 4;

    // ---- staging geometry: lane covers row 4*wid+(lane>>4), 16 floats.
    const int srow = 4 * wid + (lane >> 4);        // tile row 0..15
    const int scol = (lane & 15) * 16;             // float offset in row
    const float* gsrc = w13 + ((size_t)e * 2048 + n0 + srow) * H_DIM + scol;
    const float* usrc = w13 + ((size_t)e * 2048 + I_DIM + n0 + srow) * H_DIM + scol;
    // write slots: granules 2*(lane&15)+w, XOR row swizzle
    const int wg0 = (2 * (lane & 15) + 0) ^ (srow & 7);
    const int wg1 = (2 * (lane & 15) + 1) ^ (srow & 7);

    // ---- A row pointers (2 m-frags per wave)
    const unsigned short* ar[2];
#pragma unroll
    for (int m = 0; m < 2; ++m) {
        int r   = m0 + wid * 32 + m * 16 + fr;
        int tok = bucket[e * T_TOK + min(r, n_e - 1)] >> 1;
        ar[m] = xb + (size_t)tok * H_DIM + fq * 8;
    }

    f32x4 accg[2] = {};
    f32x4 accu[2] = {};

    // ---- prologue: stage tile 0 into buf 0
    {
        float4 g0 = *(const float4*)(gsrc + 0),  g1 = *(const float4*)(gsrc + 4);
        float4 g2 = *(const float4*)(gsrc + 8),  g3 = *(const float4*)(gsrc + 12);
        float4 u0 = *(const float4*)(usrc + 0),  u1 = *(const float4*)(usrc + 4);
        float4 u2 = *(const float4*)(usrc + 8),  u3 = *(const float4*)(usrc + 12);
        *(short8*)&sG[0][srow * 256 + wg0 * 8] = cvt8(g0, g1);
        *(short8*)&sG[0][srow * 256 + wg1 * 8] = cvt8(g2, g3);
        *(short8*)&sU[0][srow * 256 + wg0 * 8] = cvt8(u0, u1);
        *(short8*)&sU[0][srow * 256 + wg1 * 8] = cvt8(u2, u3);
    }
    __syncthreads();

    for (int t = 0; t < 8; ++t) {                  // 8 K-tiles of 256
        const int kb      = t * 256;
        const int kb_next = min(t + 1, 7) * 256;   // clamped fake tail

        // (1) A-fragment loads for tile t (L2-fast, issue FIRST)
        short8 a[8][2];
#pragma unroll
        for (int kk = 0; kk < 8; ++kk)
#pragma unroll
            for (int m = 0; m < 2; ++m)
                a[kk][m] = *(const short8*)(ar[m] + kb + kk * 32);
        __builtin_amdgcn_sched_barrier(0);   // A-loads stay above

        // (2) staging loads for tile t+1 (HBM, stay in flight over compute)
        float4 g0 = *(const float4*)(gsrc + kb_next + 0);
        float4 g1 = *(const float4*)(gsrc + kb_next + 4);
        float4 g2 = *(const float4*)(gsrc + kb_next + 8);
        float4 g3 = *(const float4*)(gsrc + kb_next + 12);
        float4 u0 = *(const float4*)(usrc + kb_next + 0);
        float4 u1 = *(const float4*)(usrc + kb_next + 4);
        float4 u2 = *(const float4*)(usrc + kb_next + 8);
        float4 u3 = *(const float4*)(usrc + kb_next + 12);
        __builtin_amdgcn_sched_barrier(0);   // staging issued here, not later

        // (3) compute tile t from buf t&1
        const unsigned short* G = sG[t & 1];
        const unsigned short* U = sU[t & 1];
#pragma unroll
        for (int kk = 0; kk < 8; ++kk) {
            int slot = (kk * 4 + fq) ^ (fr & 7);
            short8 bg = *(const short8*)&G[fr * 256 + slot * 8];
            short8 bu = *(const short8*)&U[fr * 256 + slot * 8];
#pragma unroll
            for (int m = 0; m < 2; ++m) {
                accg[m] = __builtin_amdgcn_mfma_f32_16x16x32_bf16(a[kk][m], bg, accg[m], 0, 0, 0);
                accu[m] = __builtin_amdgcn_mfma_f32_16x16x32_bf16(a[kk][m], bu, accu[m], 0, 0, 0);
            }
        }
        __builtin_amdgcn_sched_barrier(0);   // staging waits stay below MFMAs

        // (4) cvt + write tile t+1 into buf (t+1)&1 (freed by prev barrier)
        unsigned short* Gw = (unsigned short*)sG[(t + 1) & 1];
        unsigned short* Uw = (unsigned short*)sU[(t + 1) & 1];
        *(short8*)&Gw[srow * 256 + wg0 * 8] = cvt8(g0, g1);
        *(short8*)&Gw[srow * 256 + wg1 * 8] = cvt8(g2, g3);
        *(short8*)&Uw[srow * 256 + wg0 * 8] = cvt8(u0, u1);
        *(short8*)&Uw[srow * 256 + wg1 * 8] = cvt8(u2, u3);

        // (5) one barrier: writes visible, reads of this buf complete
        __syncthreads();
    }

    // epilogue: silu(gate)*up -> act (bf16)
#pragma unroll
    for (int m = 0; m < 2; ++m) {
#pragma unroll
        for (int j = 0; j < 4; ++j) {
            int r = m0 + wid * 32 + m * 16 + fq * 4 + j;
            if (r < n_e) {
                int pid = bucket[e * T_TOK + r];
                float g = accg[m][j];
                float u = accu[m][j];
                float sg = g / (1.f + expf(-g));
                *(unsigned short*)(act + (size_t)pid * I_DIM + n0 + fr) = f2bf(sg * u);
            }
        }
    }
}

// ---------------------------------------------------------------
// Kernel 3: grouped GEMM2. BM=128, BN=16, BK=256, K=1024 (4 iters).
// Same forced-concurrency register-staged pipeline.
// ---------------------------------------------------------------
__global__ __launch_bounds__(256, 2) void gemm2_kernel(
    const __hip_bfloat16* __restrict__ act, const float* __restrict__ w2,
    const int* __restrict__ count, const int* __restrict__ bucket,
    float* __restrict__ y)
{
    const int e   = blockIdx.z;
    const int n_e = count[e];
    const int m0  = blockIdx.y * 128;
    if (m0 >= n_e) return;
    const int h0  = blockIdx.x * 16;

    __shared__ unsigned short sB[2][16 * 256];

    const int tid  = threadIdx.x;
    const int lane = tid & 63;
    const int wid  = tid >> 6;
    const int fr   = lane & 15;
    const int fq   = lane >> 4;

    const int srow = 4 * wid + (lane >> 4);
    const int scol = (lane & 15) * 16;
    const float* bsrc = w2 + ((size_t)e * H_DIM + h0 + srow) * I_DIM + scol;
    const int wg0 = (2 * (lane & 15) + 0) ^ (srow & 7);
    const int wg1 = (2 * (lane & 15) + 1) ^ (srow & 7);

    const unsigned short* ar[2];
#pragma unroll
    for (int m = 0; m < 2; ++m) {
        int r   = m0 + wid * 32 + m * 16 + fr;
        int pid = bucket[e * T_TOK + min(r, n_e - 1)];
        ar[m] = (const unsigned short*)act + (size_t)pid * I_DIM + fq * 8;
    }

    f32x4 acc[2] = {};

    {
        float4 b0 = *(const float4*)(bsrc + 0),  b1 = *(const float4*)(bsrc + 4);
        float4 b2 = *(const float4*)(bsrc + 8),  b3 = *(const float4*)(bsrc + 12);
        *(short8*)&sB[0][srow * 256 + wg0 * 8] = cvt8(b0, b1);
        *(short8*)&sB[0][srow * 256 + wg1 * 8] = cvt8(b2, b3);
    }
    __syncthreads();

    for (int t = 0; t < 4; ++t) {                  // 4 K-tiles of 256
        const int kb      = t * 256;
        const int kb_next = min(t + 1, 3) * 256;

        short8 a[8][2];
#pragma unroll
        for (int kk = 0; kk < 8; ++kk)
#pragma unroll
            for (int m = 0; m < 2; ++m)
                a[kk][m] = *(const short8*)(ar[m] + kb + kk * 32);
        __builtin_amdgcn_sched_barrier(0);

        float4 b0 = *(const float4*)(bsrc + kb_next + 0);
        float4 b1 = *(const float4*)(bsrc + kb_next + 4);
        float4 b2 = *(const float4*)(bsrc + kb_next + 8);
        float4 b3 = *(const float4*)(bsrc + kb_next + 12);
        __builtin_amdgcn_sched_barrier(0);

        const unsigned short* B = sB[t & 1];
#pragma unroll
        for (int kk = 0; kk < 8; ++kk) {
            int slot = (kk * 4 + fq) ^ (fr & 7);
            short8 bb = *(const short8*)&B[fr * 256 + slot * 8];
#pragma unroll
            for (int m = 0; m < 2; ++m)
                acc[m] = __builtin_amdgcn_mfma_f32_16x16x32_bf16(a[kk][m], bb, acc[m], 0, 0, 0);
        }
        __builtin_amdgcn_sched_barrier(0);

        unsigned short* Bw = (unsigned short*)sB[(t + 1) & 1];
        *(short8*)&Bw[srow * 256 + wg0 * 8] = cvt8(b0, b1);
        *(short8*)&Bw[srow * 256 + wg1 * 8] = cvt8(b2, b3);

        __syncthreads();
    }

#pragma unroll
    for (int m = 0; m < 2; ++m) {
#pragma unroll
        for (int j = 0; j < 4; ++j) {
            int r = m0 + wid * 32 + m * 16 + fq * 4 + j;
            if (r < n_e) {
                int pid = bucket[e * T_TOK + r];
                y[(size_t)pid * H_DIM + h0 + fr] = acc[m][j];
            }
        }
    }
}

// ---------------------------------------------------------------
// Kernel 4: combine. out[t,h] = w0*y[2t,h] + w1*y[2t+1,h]
// ---------------------------------------------------------------
__global__ __launch_bounds__(256) void combine_kernel(
    const float* __restrict__ y, const float* __restrict__ pair_w,
    float* __restrict__ out)
{
    int idx = blockIdx.x * 256 + threadIdx.x;
    int t = idx >> 9;
    int c = idx & 511;
    float w0 = pair_w[2 * t + 0];
    float w1 = pair_w[2 * t + 1];
    float4 y0 = ((const float4*)(y + (size_t)(2 * t + 0) * H_DIM))[c];
    float4 y1 = ((const float4*)(y + (size_t)(2 * t + 1) * H_DIM))[c];
    float4 o;
    o.x = w0 * y0.x + w1 * y1.x;
    o.y = w0 * y0.y + w1 * y1.y;
    o.z = w0 * y0.z + w1 * y1.z;
    o.w = w0 * y0.w + w1 * y1.w;
    ((float4*)(out + (size_t)t * H_DIM))[c] = o;
}

extern "C" void kernel_launch(void* const* d_in, const int* in_sizes, int n_in,
                              void* d_out, int out_size, void* d_ws, size_t ws_size,
                              hipStream_t stream) {
    const float* x      = (const float*)d_in[0];
    const float* logits = (const float*)d_in[1];
    const float* w13    = (const float*)d_in[2];
    const float* w2     = (const float*)d_in[3];
    float* out = (float*)d_out;

    // workspace layout (16B-aligned sections)
    int*   count  = (int*)d_ws;                                        // 8
    int*   bucket = count + E_NUM;                                     // 4096
    float* pair_w = (float*)(bucket + E_NUM * T_TOK);                  // 1024
    unsigned short* xb = (unsigned short*)(pair_w + 2 * T_TOK);        // 512*2048 bf16 (2 MB)
    __hip_bfloat16* act = (__hip_bfloat16*)(xb + (size_t)T_TOK * H_DIM);   // 1024*1024 bf16 (2 MB)
    float* ybuf   = (float*)((unsigned short*)act + (size_t)2 * T_TOK * I_DIM); // 1024*2048 f32 (8 MB)

    xcvt_kernel<<<(T_TOK * H_DIM / 8) / 256, 256, 0, stream>>>(x, xb);
    routing_kernel<<<1, 512, 0, stream>>>(logits, count, bucket, pair_w);
    gemm1_silu_kernel<<<dim3(I_DIM / 16, 4, E_NUM), 256, 0, stream>>>(
        xb, w13, count, bucket, act);
    gemm2_kernel<<<dim3(H_DIM / 16, 4, E_NUM), 256, 0, stream>>>(
        act, w2, count, bucket, ybuf);
    combine_kernel<<<(T_TOK * (H_DIM / 4)) / 256, 256, 0, stream>>>(
        ybuf, pair_w, out);
}

// Round 11
// 128.777 us; speedup vs baseline: 1.1907x; 1.1907x over previous
//
#include <hip/hip_runtime.h>
#include <hip/hip_bf16.h>

#define T_TOK 512
#define H_DIM 2048
#define E_NUM 8
#define I_DIM 1024

typedef __attribute__((ext_vector_type(8))) short short8;
typedef __attribute__((ext_vector_type(4))) float f32x4;

// round-to-nearest-even float -> bf16 (as ushort)
__device__ __forceinline__ unsigned short f2bf(float f) {
    unsigned int u = __float_as_uint(f);
    u += 0x7fff + ((u >> 16) & 1);
    return (unsigned short)(u >> 16);
}

// 8 fp32 -> short8 of bf16 via packed cvt (RNE)
__device__ __forceinline__ short8 cvt8(float4 a, float4 b) {
    union { short8 s; __hip_bfloat162 h[4]; } u;
    u.h[0] = __float22bfloat162_rn(make_float2(a.x, a.y));
    u.h[1] = __float22bfloat162_rn(make_float2(a.z, a.w));
    u.h[2] = __float22bfloat162_rn(make_float2(b.x, b.y));
    u.h[3] = __float22bfloat162_rn(make_float2(b.z, b.w));
    return u.s;
}

__device__ __forceinline__ short8 cvt8v(f32x4 a, f32x4 b) {
    union { short8 s; __hip_bfloat162 h[4]; } u;
    u.h[0] = __float22bfloat162_rn(make_float2(a[0], a[1]));
    u.h[1] = __float22bfloat162_rn(make_float2(a[2], a[3]));
    u.h[2] = __float22bfloat162_rn(make_float2(b[0], b[1]));
    u.h[3] = __float22bfloat162_rn(make_float2(b[2], b[3]));
    return u.s;
}

// async global->LDS, 16B per lane; lds dest = wave-uniform base + lane*16
__device__ __forceinline__ void gload_lds16(const void* g, void* l) {
    __builtin_amdgcn_global_load_lds(
        (const __attribute__((address_space(1))) void*)g,
        (__attribute__((address_space(3))) void*)l, 16, 0, 0);
}

// ---------------------------------------------------------------
// xcvt: x -> bf16 (1M elems, 8/thread)
// ---------------------------------------------------------------
__global__ __launch_bounds__(256) void xcvt_kernel(
    const float* __restrict__ x, unsigned short* __restrict__ xb)
{
    int i = (blockIdx.x * 256 + threadIdx.x) * 8;
    float4 v0 = *(const float4*)(x + i);
    float4 v1 = *(const float4*)(x + i + 4);
    *(short8*)(xb + i) = cvt8(v0, v1);
}

// ---------------------------------------------------------------
// conv13: PURE LINEAR STREAM convert w13 fp32 -> bf16, same layout.
// This is the d2d-copy access shape (read 32B/lane seq, write 16B).
// ---------------------------------------------------------------
__global__ __launch_bounds__(256) void conv13_kernel(
    const float* __restrict__ w13, unsigned short* __restrict__ wb)
{
    size_t i = ((size_t)blockIdx.x * 256 + threadIdx.x) * 8;
    f32x4 v0 = __builtin_nontemporal_load((const f32x4*)(w13 + i));
    f32x4 v1 = __builtin_nontemporal_load((const f32x4*)(w13 + i + 4));
    *(short8*)(wb + i) = cvt8v(v0, v1);
}

// ---------------------------------------------------------------
// routing. 1 block, 512 threads.
// ---------------------------------------------------------------
__global__ __launch_bounds__(512) void routing_kernel(
    const float* __restrict__ logits,
    int* __restrict__ count, int* __restrict__ bucket,
    float* __restrict__ pair_w)
{
    int t = threadIdx.x;
    if (t < E_NUM) count[t] = 0;
    __syncthreads();

    float p[E_NUM];
    float m = -INFINITY;
#pragma unroll
    for (int e = 0; e < E_NUM; ++e) {
        p[e] = logits[t * E_NUM + e];
        m = fmaxf(m, p[e]);
    }
#pragma unroll
    for (int e = 0; e < E_NUM; ++e) p[e] = expf(p[e] - m);
    int i0 = 0;
#pragma unroll
    for (int e = 1; e < E_NUM; ++e) if (p[e] > p[i0]) i0 = e;
    int i1 = (i0 == 0) ? 1 : 0;
#pragma unroll
    for (int e = 0; e < E_NUM; ++e) if (e != i0 && p[e] > p[i1]) i1 = e;
    float denom = p[i0] + p[i1];
    pair_w[2 * t + 0] = p[i0] / denom;
    pair_w[2 * t + 1] = p[i1] / denom;

    int pos0 = atomicAdd(&count[i0], 1);
    bucket[i0 * T_TOK + pos0] = 2 * t + 0;
    int pos1 = atomicAdd(&count[i1], 1);
    bucket[i1 * T_TOK + pos1] = 2 * t + 1;
}

// ---------------------------------------------------------------
// gemm1 (round-5 proven ring-4 DMA structure, bf16 weights).
// BM=64, BN=32 gate + 32 up, BK=64. Ring-4 LDS (64 KB), 3 stages in
// flight, vmcnt(12) counted (4 instrs/stage). All-bf16 staging.
// 4 waves 2x2: wave = rows wr*32..+32, cols wc*16..+16 (g and u).
// ---------------------------------------------------------------
__global__ __launch_bounds__(256, 2) void gemm1_silu_kernel(
    const unsigned short* __restrict__ xb, const unsigned short* __restrict__ w13b,
    const int* __restrict__ count, const int* __restrict__ bucket,
    __hip_bfloat16* __restrict__ act)
{
    const int e   = blockIdx.z;
    const int n_e = count[e];
    const int m0  = blockIdx.y * 64;
    if (m0 >= n_e) return;
    const int n0  = blockIdx.x * 32;

    __shared__ unsigned short sA[4][64 * 64];  // 8 KB/buf
    __shared__ unsigned short sG[4][32 * 64];  // 4 KB/buf
    __shared__ unsigned short sU[4][32 * 64];  // 4 KB/buf

    const int tid  = threadIdx.x;
    const int lane = tid & 63;
    const int wid  = tid >> 6;     // 0..3
    const int fr   = lane & 15;
    const int fq   = lane >> 4;
    const int wr   = wid >> 1;
    const int wc   = wid & 1;

    const int swz = (((lane & 7) ^ ((lane >> 3) & 7)) << 3);  // source granule*8

    // A: 2 instrs/wave, 8 rows each
    const unsigned short* srcA[2];
#pragma unroll
    for (int i = 0; i < 2; ++i) {
        int row = wid * 16 + i * 8 + (lane >> 3);
        int tok = bucket[e * T_TOK + min(m0 + row, n_e - 1)] >> 1;
        srcA[i] = xb + (size_t)tok * H_DIM + swz;
    }
    // G/U: 1 instr/wave, 8 rows (bf16 128B rows)
    const int grow = wid * 8 + (lane >> 3);
    const unsigned short* srcG = w13b + ((size_t)e * 2048 + n0 + grow) * H_DIM + swz;
    const unsigned short* srcU = w13b + ((size_t)e * 2048 + I_DIM + n0 + grow) * H_DIM + swz;

    auto stage = [&](int t, int buf) {
        int kb = t * 64;
        gload_lds16(srcA[0] + kb, &sA[buf][(wid * 16) * 64]);
        gload_lds16(srcA[1] + kb, &sA[buf][(wid * 16 + 8) * 64]);
        gload_lds16(srcG + kb, &sG[buf][(wid * 8) * 64]);
        gload_lds16(srcU + kb, &sU[buf][(wid * 8) * 64]);
    };

    f32x4 accg[2] = {};
    f32x4 accu[2] = {};

    stage(0, 0); stage(1, 1); stage(2, 2);

    for (int t = 0; t < 32; ++t) {
        stage(min(t + 3, 31), (t + 3) & 3);                // clamped fake tail
        asm volatile("s_waitcnt vmcnt(12)" ::: "memory");  // own stage(t) landed
        __builtin_amdgcn_s_barrier();                      // all waves' stage(t)

        const int buf = t & 3;
        short8 a[2][2], bg[2], bu[2];
#pragma unroll
        for (int kk = 0; kk < 2; ++kk) {
            int slot = ((kk * 4 + fq) ^ (fr & 7)) * 8;
#pragma unroll
            for (int m = 0; m < 2; ++m)
                a[kk][m] = *(const short8*)&sA[buf][(wr * 32 + m * 16 + fr) * 64 + slot];
            bg[kk] = *(const short8*)&sG[buf][(wc * 16 + fr) * 64 + slot];
            bu[kk] = *(const short8*)&sU[buf][(wc * 16 + fr) * 64 + slot];
        }
        asm volatile("s_waitcnt lgkmcnt(0)" ::: "memory"); // reads retired
        __builtin_amdgcn_s_barrier();                      // buffer reusable

#pragma unroll
        for (int kk = 0; kk < 2; ++kk)
#pragma unroll
            for (int m = 0; m < 2; ++m) {
                accg[m] = __builtin_amdgcn_mfma_f32_16x16x32_bf16(a[kk][m], bg[kk], accg[m], 0, 0, 0);
                accu[m] = __builtin_amdgcn_mfma_f32_16x16x32_bf16(a[kk][m], bu[kk], accu[m], 0, 0, 0);
            }
    }
    asm volatile("s_waitcnt vmcnt(0)" ::: "memory");       // drain fakes

    // epilogue: silu(gate)*up -> act (bf16)
#pragma unroll
    for (int m = 0; m < 2; ++m) {
#pragma unroll
        for (int j = 0; j < 4; ++j) {
            int r = m0 + wr * 32 + m * 16 + fq * 4 + j;
            if (r < n_e) {
                int pid = bucket[e * T_TOK + r];
                float g = accg[m][j];
                float u = accu[m][j];
                float sg = g / (1.f + expf(-g));
                int col = n0 + wc * 16 + fr;
                *(unsigned short*)(act + (size_t)pid * I_DIM + col) = f2bf(sg * u);
            }
        }
    }
}

// ---------------------------------------------------------------
// gemm2 (round-6 passing kernel, verbatim). BM=64, BN=32, BK=64.
// Ring-4 (64 KB), vmcnt(12). A = act bf16, B = w2 fp32 cvt at read.
// ---------------------------------------------------------------
__global__ __launch_bounds__(256) void gemm2_kernel(
    const __hip_bfloat16* __restrict__ act, const float* __restrict__ w2,
    const int* __restrict__ count, const int* __restrict__ bucket,
    float* __restrict__ y)
{
    const int e   = blockIdx.z;
    const int n_e = count[e];
    const int m0  = blockIdx.y * 64;
    if (m0 >= n_e) return;
    const int h0  = blockIdx.x * 32;

    __shared__ unsigned short sA[4][64 * 64];  // bf16 8 KB/buf
    __shared__ float sB[4][32 * 64];           // f32  8 KB/buf

    const int tid  = threadIdx.x;
    const int lane = tid & 63;
    const int wid  = tid >> 6;
    const int fr   = lane & 15;
    const int fq   = lane >> 4;
    const int wr   = wid >> 1;
    const int wc   = wid & 1;

    const unsigned short* aptr[2];
#pragma unroll
    for (int i = 0; i < 2; ++i) {
        int r   = 16 * wid + 8 * i + (lane >> 3);
        int gsl = (lane & 7) ^ (r & 7);
        int pid = bucket[e * T_TOK + min(m0 + r, n_e - 1)];
        aptr[i] = (const unsigned short*)act + (size_t)pid * I_DIM + gsl * 8;
    }
    const float* bptr[2];
#pragma unroll
    for (int i = 0; i < 2; ++i) {
        int r   = 8 * wid + 4 * i + (lane >> 4);
        int gsl = (lane & 15) ^ (r & 7);
        bptr[i] = w2 + ((size_t)e * H_DIM + h0 + r) * I_DIM + gsl * 4;
    }

    auto stage = [&](int kb, int buf) {
#pragma unroll
        for (int i = 0; i < 2; ++i)
            gload_lds16(aptr[i] + kb, &sA[buf][(16 * wid + 8 * i) * 64]);
#pragma unroll
        for (int i = 0; i < 2; ++i)
            gload_lds16(bptr[i] + kb, &sB[buf][(8 * wid + 4 * i) * 64]);
    };

    f32x4 acc[2] = {};

    stage(0, 0); stage(64, 1); stage(128, 2);

    for (int t = 0; t < 16; ++t) {
        stage(min(t + 3, 15) * 64, (t + 3) & 3);
        asm volatile("s_waitcnt vmcnt(12)" ::: "memory");
        __builtin_amdgcn_s_barrier();

        const int buf = t & 3;
        short8 a[2][2], b[2];
#pragma unroll
        for (int kk = 0; kk < 2; ++kk) {
#pragma unroll
            for (int m = 0; m < 2; ++m) {
                int r    = wr * 32 + m * 16 + fr;
                int slot = (kk * 4 + fq) ^ (r & 7);
                a[kk][m] = *(const short8*)&sA[buf][r * 64 + slot * 8];
            }
            {
                int r  = wc * 16 + fr;
                int s0 = (kk * 8 + fq * 2) ^ (r & 7);
                const float* bb = &sB[buf][r * 64];
                b[kk] = cvt8(*(const float4*)(bb + s0 * 4), *(const float4*)(bb + (s0 ^ 1) * 4));
            }
        }
        asm volatile("s_waitcnt lgkmcnt(0)" ::: "memory");
        __builtin_amdgcn_s_barrier();

#pragma unroll
        for (int kk = 0; kk < 2; ++kk)
#pragma unroll
            for (int m = 0; m < 2; ++m)
                acc[m] = __builtin_amdgcn_mfma_f32_16x16x32_bf16(a[kk][m], b[kk], acc[m], 0, 0, 0);
    }
    asm volatile("s_waitcnt vmcnt(0)" ::: "memory");

#pragma unroll
    for (int m = 0; m < 2; ++m) {
#pragma unroll
        for (int j = 0; j < 4; ++j) {
            int r = m0 + wr * 32 + m * 16 + fq * 4 + j;
            if (r < n_e) {
                int pid = bucket[e * T_TOK + r];
                y[(size_t)pid * H_DIM + h0 + wc * 16 + fr] = acc[m][j];
            }
        }
    }
}

// ---------------------------------------------------------------
// combine: out[t,h] = w0*y[2t,h] + w1*y[2t+1,h]
// ---------------------------------------------------------------
__global__ __launch_bounds__(256) void combine_kernel(
    const float* __restrict__ y, const float* __restrict__ pair_w,
    float* __restrict__ out)
{
    int idx = blockIdx.x * 256 + threadIdx.x;
    int t = idx >> 9;
    int c = idx & 511;
    float w0 = pair_w[2 * t + 0];
    float w1 = pair_w[2 * t + 1];
    float4 y0 = ((const float4*)(y + (size_t)(2 * t + 0) * H_DIM))[c];
    float4 y1 = ((const float4*)(y + (size_t)(2 * t + 1) * H_DIM))[c];
    float4 o;
    o.x = w0 * y0.x + w1 * y1.x;
    o.y = w0 * y0.y + w1 * y1.y;
    o.z = w0 * y0.z + w1 * y1.z;
    o.w = w0 * y0.w + w1 * y1.w;
    ((float4*)(out + (size_t)t * H_DIM))[c] = o;
}

// ================= FALLBACK gemm1 (round-8 passing register path) =============
__global__ __launch_bounds__(256, 2) void gemm1_fb_kernel(
    const unsigned short* __restrict__ xb, const float* __restrict__ w13,
    const int* __restrict__ count, const int* __restrict__ bucket,
    __hip_bfloat16* __restrict__ act)
{
    const int e   = blockIdx.z;
    const int n_e = count[e];
    const int m0  = blockIdx.y * 128;
    if (m0 >= n_e) return;
    const int n0  = blockIdx.x * 16;

    __shared__ unsigned short sG[2][16 * 256];
    __shared__ unsigned short sU[2][16 * 256];

    const int tid  = threadIdx.x;
    const int lane = tid & 63;
    const int wid  = tid >> 6;
    const int fr   = lane & 15;
    const int fq   = lane >> 4;

    const int srow = 4 * wid + (lane >> 4);
    const int scol = (lane & 15) * 16;
    const float* gsrc = w13 + ((size_t)e * 2048 + n0 + srow) * H_DIM + scol;
    const float* usrc = w13 + ((size_t)e * 2048 + I_DIM + n0 + srow) * H_DIM + scol;
    const int wg0 = (2 * (lane & 15) + 0) ^ (srow & 7);
    const int wg1 = (2 * (lane & 15) + 1) ^ (srow & 7);

    const unsigned short* ar[2];
#pragma unroll
    for (int m = 0; m < 2; ++m) {
        int r   = m0 + wid * 32 + m * 16 + fr;
        int tok = bucket[e * T_TOK + min(r, n_e - 1)] >> 1;
        ar[m] = xb + (size_t)tok * H_DIM + fq * 8;
    }

    f32x4 accg[2] = {};
    f32x4 accu[2] = {};

    {
        float4 g0 = *(const float4*)(gsrc + 0),  g1 = *(const float4*)(gsrc + 4);
        float4 g2 = *(const float4*)(gsrc + 8),  g3 = *(const float4*)(gsrc + 12);
        float4 u0 = *(const float4*)(usrc + 0),  u1 = *(const float4*)(usrc + 4);
        float4 u2 = *(const float4*)(usrc + 8),  u3 = *(const float4*)(usrc + 12);
        *(short8*)&sG[0][srow * 256 + wg0 * 8] = cvt8(g0, g1);
        *(short8*)&sG[0][srow * 256 + wg1 * 8] = cvt8(g2, g3);
        *(short8*)&sU[0][srow * 256 + wg0 * 8] = cvt8(u0, u1);
        *(short8*)&sU[0][srow * 256 + wg1 * 8] = cvt8(u2, u3);
    }
    __syncthreads();

    for (int t = 0; t < 8; ++t) {
        const int kb      = t * 256;
        const int kb_next = min(t + 1, 7) * 256;

        short8 a[8][2];
#pragma unroll
        for (int kk = 0; kk < 8; ++kk)
#pragma unroll
            for (int m = 0; m < 2; ++m)
                a[kk][m] = *(const short8*)(ar[m] + kb + kk * 32);

        float4 g0 = *(const float4*)(gsrc + kb_next + 0);
        float4 g1 = *(const float4*)(gsrc + kb_next + 4);
        float4 g2 = *(const float4*)(gsrc + kb_next + 8);
        float4 g3 = *(const float4*)(gsrc + kb_next + 12);
        float4 u0 = *(const float4*)(usrc + kb_next + 0);
        float4 u1 = *(const float4*)(usrc + kb_next + 4);
        float4 u2 = *(const float4*)(usrc + kb_next + 8);
        float4 u3 = *(const float4*)(usrc + kb_next + 12);

        const unsigned short* G = sG[t & 1];
        const unsigned short* U = sU[t & 1];
#pragma unroll
        for (int kk = 0; kk < 8; ++kk) {
            int slot = (kk * 4 + fq) ^ (fr & 7);
            short8 bg = *(const short8*)&G[fr * 256 + slot * 8];
            short8 bu = *(const short8*)&U[fr * 256 + slot * 8];
#pragma unroll
            for (int m = 0; m < 2; ++m) {
                accg[m] = __builtin_amdgcn_mfma_f32_16x16x32_bf16(a[kk][m], bg, accg[m], 0, 0, 0);
                accu[m] = __builtin_amdgcn_mfma_f32_16x16x32_bf16(a[kk][m], bu, accu[m], 0, 0, 0);
            }
        }

        unsigned short* Gw = (unsigned short*)sG[(t + 1) & 1];
        unsigned short* Uw = (unsigned short*)sU[(t + 1) & 1];
        *(short8*)&Gw[srow * 256 + wg0 * 8] = cvt8(g0, g1);
        *(short8*)&Gw[srow * 256 + wg1 * 8] = cvt8(g2, g3);
        *(short8*)&Uw[srow * 256 + wg0 * 8] = cvt8(u0, u1);
        *(short8*)&Uw[srow * 256 + wg1 * 8] = cvt8(u2, u3);
        __syncthreads();
    }

#pragma unroll
    for (int m = 0; m < 2; ++m) {
#pragma unroll
        for (int j = 0; j < 4; ++j) {
            int r = m0 + wid * 32 + m * 16 + fq * 4 + j;
            if (r < n_e) {
                int pid = bucket[e * T_TOK + r];
                float g = accg[m][j];
                float u = accu[m][j];
                float sg = g / (1.f + expf(-g));
                *(unsigned short*)(act + (size_t)pid * I_DIM + n0 + fr) = f2bf(sg * u);
            }
        }
    }
}

extern "C" void kernel_launch(void* const* d_in, const int* in_sizes, int n_in,
                              void* d_out, int out_size, void* d_ws, size_t ws_size,
                              hipStream_t stream) {
    const float* x      = (const float*)d_in[0];
    const float* logits = (const float*)d_in[1];
    const float* w13    = (const float*)d_in[2];
    const float* w2     = (const float*)d_in[3];
    float* out = (float*)d_out;

    char* ws = (char*)d_ws;
    // disjoint layout (bytes):
    int*   count  = (int*)(ws + 0);                         // 256 B
    int*   bucket = (int*)(ws + 256);                       // 16 KB -> 16640
    float* pair_w = (float*)(ws + 16640);                   // 4 KB  -> 20736
    unsigned short* xb  = (unsigned short*)(ws + 24576);    // 2 MB  -> 2,121,728
    __hip_bfloat16* act = (__hip_bfloat16*)(ws + 2121728);  // 2 MB  -> 4,218,880
    const size_t O_W13B = 4218880;
    unsigned short* w13b = (unsigned short*)(ws + O_W13B);  // 64 MB -> 71,327,744
    float* ybuf_big = (float*)(ws + 71327744);              // 8 MB  -> 79,716,352
    float* ybuf_fb  = (float*)(ws + O_W13B);                // fallback: 8 MB at w13b slot
    const size_t NEED = 79716352;

    xcvt_kernel<<<(T_TOK * H_DIM / 8) / 256, 256, 0, stream>>>(x, xb);
    routing_kernel<<<1, 512, 0, stream>>>(logits, count, bucket, pair_w);

    if (ws_size >= NEED) {
        conv13_kernel<<<((size_t)E_NUM * 2 * I_DIM * H_DIM / 8) / 256, 256, 0, stream>>>(w13, w13b);
        gemm1_silu_kernel<<<dim3(I_DIM / 32, T_TOK / 64, E_NUM), 256, 0, stream>>>(
            xb, w13b, count, bucket, act);
        gemm2_kernel<<<dim3(H_DIM / 32, T_TOK / 64, E_NUM), 256, 0, stream>>>(
            act, w2, count, bucket, ybuf_big);
        combine_kernel<<<(T_TOK * (H_DIM / 4)) / 256, 256, 0, stream>>>(ybuf_big, pair_w, out);
    } else {
        gemm1_fb_kernel<<<dim3(I_DIM / 16, 4, E_NUM), 256, 0, stream>>>(
            xb, w13, count, bucket, act);
        gemm2_kernel<<<dim3(H_DIM / 32, T_TOK / 64, E_NUM), 256, 0, stream>>>(
            act, w2, count, bucket, ybuf_fb);
        combine_kernel<<<(T_TOK * (H_DIM / 4)) / 256, 256, 0, stream>>>(ybuf_fb, pair_w, out);
    }
}

// Round 12
// 114.350 us; speedup vs baseline: 1.3409x; 1.1262x over previous
//
#include <hip/hip_runtime.h>
#include <hip/hip_bf16.h>

#define T_TOK 512
#define H_DIM 2048
#define E_NUM 8
#define I_DIM 1024

typedef __attribute__((ext_vector_type(8))) short short8;
typedef __attribute__((ext_vector_type(4))) float f32x4;

// round-to-nearest-even float -> bf16 (as ushort)
__device__ __forceinline__ unsigned short f2bf(float f) {
    unsigned int u = __float_as_uint(f);
    u += 0x7fff + ((u >> 16) & 1);
    return (unsigned short)(u >> 16);
}

// 8 fp32 -> short8 of bf16 via packed cvt (RNE)
__device__ __forceinline__ short8 cvt8(float4 a, float4 b) {
    union { short8 s; __hip_bfloat162 h[4]; } u;
    u.h[0] = __float22bfloat162_rn(make_float2(a.x, a.y));
    u.h[1] = __float22bfloat162_rn(make_float2(a.z, a.w));
    u.h[2] = __float22bfloat162_rn(make_float2(b.x, b.y));
    u.h[3] = __float22bfloat162_rn(make_float2(b.z, b.w));
    return u.s;
}

__device__ __forceinline__ short8 cvt8v(f32x4 a, f32x4 b) {
    union { short8 s; __hip_bfloat162 h[4]; } u;
    u.h[0] = __float22bfloat162_rn(make_float2(a[0], a[1]));
    u.h[1] = __float22bfloat162_rn(make_float2(a[2], a[3]));
    u.h[2] = __float22bfloat162_rn(make_float2(b[0], b[1]));
    u.h[3] = __float22bfloat162_rn(make_float2(b[2], b[3]));
    return u.s;
}

// async global->LDS, 16B per lane; lds dest = wave-uniform base + lane*16
__device__ __forceinline__ void gload_lds16(const void* g, void* l) {
    __builtin_amdgcn_global_load_lds(
        (const __attribute__((address_space(1))) void*)g,
        (__attribute__((address_space(3))) void*)l, 16, 0, 0);
}

// ---------------------------------------------------------------
// xcvt: x -> bf16 (1M elems, 8/thread)
// ---------------------------------------------------------------
__global__ __launch_bounds__(256) void xcvt_kernel(
    const float* __restrict__ x, unsigned short* __restrict__ xb)
{
    int i = (blockIdx.x * 256 + threadIdx.x) * 8;
    float4 v0 = *(const float4*)(x + i);
    float4 v1 = *(const float4*)(x + i + 4);
    *(short8*)(xb + i) = cvt8(v0, v1);
}

// ---------------------------------------------------------------
// conv13: PURE LINEAR STREAM convert w13 fp32 -> bf16, same layout.
// ---------------------------------------------------------------
__global__ __launch_bounds__(256) void conv13_kernel(
    const float* __restrict__ w13, unsigned short* __restrict__ wb)
{
    size_t i = ((size_t)blockIdx.x * 256 + threadIdx.x) * 8;
    f32x4 v0 = __builtin_nontemporal_load((const f32x4*)(w13 + i));
    f32x4 v1 = __builtin_nontemporal_load((const f32x4*)(w13 + i + 4));
    *(short8*)(wb + i) = cvt8v(v0, v1);
}

// ---------------------------------------------------------------
// routing. 1 block, 512 threads.
// ---------------------------------------------------------------
__global__ __launch_bounds__(512) void routing_kernel(
    const float* __restrict__ logits,
    int* __restrict__ count, int* __restrict__ bucket,
    float* __restrict__ pair_w)
{
    int t = threadIdx.x;
    if (t < E_NUM) count[t] = 0;
    __syncthreads();

    float p[E_NUM];
    float m = -INFINITY;
#pragma unroll
    for (int e = 0; e < E_NUM; ++e) {
        p[e] = logits[t * E_NUM + e];
        m = fmaxf(m, p[e]);
    }
#pragma unroll
    for (int e = 0; e < E_NUM; ++e) p[e] = expf(p[e] - m);
    int i0 = 0;
#pragma unroll
    for (int e = 1; e < E_NUM; ++e) if (p[e] > p[i0]) i0 = e;
    int i1 = (i0 == 0) ? 1 : 0;
#pragma unroll
    for (int e = 0; e < E_NUM; ++e) if (e != i0 && p[e] > p[i1]) i1 = e;
    float denom = p[i0] + p[i1];
    pair_w[2 * t + 0] = p[i0] / denom;
    pair_w[2 * t + 1] = p[i1] / denom;

    int pos0 = atomicAdd(&count[i0], 1);
    bucket[i0 * T_TOK + pos0] = 2 * t + 0;
    int pos1 = atomicAdd(&count[i1], 1);
    bucket[i1 * T_TOK + pos1] = 2 * t + 1;
}

// ---------------------------------------------------------------
// gemm1: BM=128, BN=32g+32u, BK=64. Ring-3 (72 KB), 2-ahead,
// vmcnt(12) (6 instrs/stage). All-bf16 DMA staging (w13b L3-hot).
// 4 waves 2x2: wave = 64 rows (4 m-frags) x 16 cols (g and u).
// ---------------------------------------------------------------
__global__ __launch_bounds__(256, 2) void gemm1_silu_kernel(
    const unsigned short* __restrict__ xb, const unsigned short* __restrict__ w13b,
    const int* __restrict__ count, const int* __restrict__ bucket,
    __hip_bfloat16* __restrict__ act)
{
    const int e   = blockIdx.z;
    const int n_e = count[e];
    const int m0  = blockIdx.y * 128;
    if (m0 >= n_e) return;
    const int n0  = blockIdx.x * 32;

    __shared__ unsigned short sA[3][128 * 64];  // 16 KB/buf
    __shared__ unsigned short sG[3][32 * 64];   // 4 KB/buf
    __shared__ unsigned short sU[3][32 * 64];   // 4 KB/buf

    const int tid  = threadIdx.x;
    const int lane = tid & 63;
    const int wid  = tid >> 6;     // 0..3
    const int fr   = lane & 15;
    const int fq   = lane >> 4;
    const int wr   = wid >> 1;
    const int wc   = wid & 1;

    const int swz = (((lane & 7) ^ ((lane >> 3) & 7)) << 3);  // source granule*8

    // A: 4 instrs/wave, 8 rows each (wave covers rows wid*32..+32)
    const unsigned short* srcA[4];
#pragma unroll
    for (int i = 0; i < 4; ++i) {
        int row = wid * 32 + i * 8 + (lane >> 3);
        int tok = bucket[e * T_TOK + min(m0 + row, n_e - 1)] >> 1;
        srcA[i] = xb + (size_t)tok * H_DIM + swz;
    }
    // G/U: 1 instr/wave, 8 rows (bf16 128B rows)
    const int grow = wid * 8 + (lane >> 3);
    const unsigned short* srcG = w13b + ((size_t)e * 2048 + n0 + grow) * H_DIM + swz;
    const unsigned short* srcU = w13b + ((size_t)e * 2048 + I_DIM + n0 + grow) * H_DIM + swz;

    auto stage = [&](int t, int buf) {
        int kb = t * 64;
#pragma unroll
        for (int i = 0; i < 4; ++i)
            gload_lds16(srcA[i] + kb, &sA[buf][(wid * 32 + i * 8) * 64]);
        gload_lds16(srcG + kb, &sG[buf][(wid * 8) * 64]);
        gload_lds16(srcU + kb, &sU[buf][(wid * 8) * 64]);
    };

    f32x4 accg[4] = {};
    f32x4 accu[4] = {};

    stage(0, 0); stage(1, 1);

    for (int t = 0; t < 32; ++t) {
        stage(min(t + 2, 31), (t + 2) % 3);                // clamped fake tail
        asm volatile("s_waitcnt vmcnt(12)" ::: "memory");  // own stage(t) landed
        __builtin_amdgcn_s_barrier();                      // all waves' stage(t)

        const int buf = t % 3;
        short8 a[2][4], bg[2], bu[2];
#pragma unroll
        for (int kk = 0; kk < 2; ++kk) {
            int slot = ((kk * 4 + fq) ^ (fr & 7)) * 8;
#pragma unroll
            for (int m = 0; m < 4; ++m)
                a[kk][m] = *(const short8*)&sA[buf][(wr * 64 + m * 16 + fr) * 64 + slot];
            bg[kk] = *(const short8*)&sG[buf][(wc * 16 + fr) * 64 + slot];
            bu[kk] = *(const short8*)&sU[buf][(wc * 16 + fr) * 64 + slot];
        }
        asm volatile("s_waitcnt lgkmcnt(0)" ::: "memory"); // reads retired
        __builtin_amdgcn_s_barrier();                      // buffer reusable

#pragma unroll
        for (int kk = 0; kk < 2; ++kk)
#pragma unroll
            for (int m = 0; m < 4; ++m) {
                accg[m] = __builtin_amdgcn_mfma_f32_16x16x32_bf16(a[kk][m], bg[kk], accg[m], 0, 0, 0);
                accu[m] = __builtin_amdgcn_mfma_f32_16x16x32_bf16(a[kk][m], bu[kk], accu[m], 0, 0, 0);
            }
    }
    asm volatile("s_waitcnt vmcnt(0)" ::: "memory");       // drain fakes

    // epilogue: silu(gate)*up -> act (bf16)
#pragma unroll
    for (int m = 0; m < 4; ++m) {
#pragma unroll
        for (int j = 0; j < 4; ++j) {
            int r = m0 + wr * 64 + m * 16 + fq * 4 + j;
            if (r < n_e) {
                int pid = bucket[e * T_TOK + r];
                float g = accg[m][j];
                float u = accu[m][j];
                float sg = g / (1.f + expf(-g));
                int col = n0 + wc * 16 + fr;
                *(unsigned short*)(act + (size_t)pid * I_DIM + col) = f2bf(sg * u);
            }
        }
    }
}

// ---------------------------------------------------------------
// gemm2: BM=128, BN=32, BK=64, K=1024 (16 tiles). Ring-3 (72 KB),
// 2-ahead, vmcnt(12) (6 instrs/stage). A = act bf16 gathered,
// B = w2 fp32 (L3-hot) cvt at read.
// ---------------------------------------------------------------
__global__ __launch_bounds__(256, 2) void gemm2_kernel(
    const __hip_bfloat16* __restrict__ act, const float* __restrict__ w2,
    const int* __restrict__ count, const int* __restrict__ bucket,
    float* __restrict__ y)
{
    const int e   = blockIdx.z;
    const int n_e = count[e];
    const int m0  = blockIdx.y * 128;
    if (m0 >= n_e) return;
    const int h0  = blockIdx.x * 32;

    __shared__ unsigned short sA[3][128 * 64];  // bf16 16 KB/buf
    __shared__ float sB[3][32 * 64];            // f32   8 KB/buf

    const int tid  = threadIdx.x;
    const int lane = tid & 63;
    const int wid  = tid >> 6;
    const int fr   = lane & 15;
    const int fq   = lane >> 4;
    const int wr   = wid >> 1;
    const int wc   = wid & 1;

    // A: 4 instrs/wave (8 rows each, bf16 128B rows)
    const unsigned short* aptr[4];
#pragma unroll
    for (int i = 0; i < 4; ++i) {
        int r   = wid * 32 + i * 8 + (lane >> 3);
        int gsl = (lane & 7) ^ (r & 7);
        int pid = bucket[e * T_TOK + min(m0 + r, n_e - 1)];
        aptr[i] = (const unsigned short*)act + (size_t)pid * I_DIM + gsl * 8;
    }
    // B: 2 instrs/wave (4 rows each, fp32 256B rows)
    const float* bptr[2];
#pragma unroll
    for (int i = 0; i < 2; ++i) {
        int r   = 8 * wid + 4 * i + (lane >> 4);
        int gsl = (lane & 15) ^ (r & 7);
        bptr[i] = w2 + ((size_t)e * H_DIM + h0 + r) * I_DIM + gsl * 4;
    }

    auto stage = [&](int t, int buf) {
        int kb = t * 64;
#pragma unroll
        for (int i = 0; i < 4; ++i)
            gload_lds16(aptr[i] + kb, &sA[buf][(wid * 32 + i * 8) * 64]);
#pragma unroll
        for (int i = 0; i < 2; ++i)
            gload_lds16(bptr[i] + kb, &sB[buf][(8 * wid + 4 * i) * 64]);
    };

    f32x4 acc[4] = {};

    stage(0, 0); stage(1, 1);

    for (int t = 0; t < 16; ++t) {
        stage(min(t + 2, 15), (t + 2) % 3);
        asm volatile("s_waitcnt vmcnt(12)" ::: "memory");
        __builtin_amdgcn_s_barrier();

        const int buf = t % 3;
        short8 a[2][4], b[2];
#pragma unroll
        for (int kk = 0; kk < 2; ++kk) {
#pragma unroll
            for (int m = 0; m < 4; ++m) {
                int r    = wr * 64 + m * 16 + fr;
                int slot = (kk * 4 + fq) ^ (r & 7);
                a[kk][m] = *(const short8*)&sA[buf][r * 64 + slot * 8];
            }
            {
                int r  = wc * 16 + fr;
                int s0 = (kk * 8 + fq * 2) ^ (r & 7);
                const float* bb = &sB[buf][r * 64];
                b[kk] = cvt8(*(const float4*)(bb + s0 * 4), *(const float4*)(bb + (s0 ^ 1) * 4));
            }
        }
        asm volatile("s_waitcnt lgkmcnt(0)" ::: "memory");
        __builtin_amdgcn_s_barrier();

#pragma unroll
        for (int kk = 0; kk < 2; ++kk)
#pragma unroll
            for (int m = 0; m < 4; ++m)
                acc[m] = __builtin_amdgcn_mfma_f32_16x16x32_bf16(a[kk][m], b[kk], acc[m], 0, 0, 0);
    }
    asm volatile("s_waitcnt vmcnt(0)" ::: "memory");

#pragma unroll
    for (int m = 0; m < 4; ++m) {
#pragma unroll
        for (int j = 0; j < 4; ++j) {
            int r = m0 + wr * 64 + m * 16 + fq * 4 + j;
            if (r < n_e) {
                int pid = bucket[e * T_TOK + r];
                y[(size_t)pid * H_DIM + h0 + wc * 16 + fr] = acc[m][j];
            }
        }
    }
}

// ---------------------------------------------------------------
// combine: out[t,h] = w0*y[2t,h] + w1*y[2t+1,h]
// ---------------------------------------------------------------
__global__ __launch_bounds__(256) void combine_kernel(
    const float* __restrict__ y, const float* __restrict__ pair_w,
    float* __restrict__ out)
{
    int idx = blockIdx.x * 256 + threadIdx.x;
    int t = idx >> 9;
    int c = idx & 511;
    float w0 = pair_w[2 * t + 0];
    float w1 = pair_w[2 * t + 1];
    float4 y0 = ((const float4*)(y + (size_t)(2 * t + 0) * H_DIM))[c];
    float4 y1 = ((const float4*)(y + (size_t)(2 * t + 1) * H_DIM))[c];
    float4 o;
    o.x = w0 * y0.x + w1 * y1.x;
    o.y = w0 * y0.y + w1 * y1.y;
    o.z = w0 * y0.z + w1 * y1.z;
    o.w = w0 * y0.w + w1 * y1.w;
    ((float4*)(out + (size_t)t * H_DIM))[c] = o;
}

// ================= FALLBACK gemm1 (round-8 passing register path) =============
__global__ __launch_bounds__(256, 2) void gemm1_fb_kernel(
    const unsigned short* __restrict__ xb, const float* __restrict__ w13,
    const int* __restrict__ count, const int* __restrict__ bucket,
    __hip_bfloat16* __restrict__ act)
{
    const int e   = blockIdx.z;
    const int n_e = count[e];
    const int m0  = blockIdx.y * 128;
    if (m0 >= n_e) return;
    const int n0  = blockIdx.x * 16;

    __shared__ unsigned short sG[2][16 * 256];
    __shared__ unsigned short sU[2][16 * 256];

    const int tid  = threadIdx.x;
    const int lane = tid & 63;
    const int wid  = tid >> 6;
    const int fr   = lane & 15;
    const int fq   = lane >> 4;

    const int srow = 4 * wid + (lane >> 4);
    const int scol = (lane & 15) * 16;
    const float* gsrc = w13 + ((size_t)e * 2048 + n0 + srow) * H_DIM + scol;
    const float* usrc = w13 + ((size_t)e * 2048 + I_DIM + n0 + srow) * H_DIM + scol;
    const int wg0 = (2 * (lane & 15) + 0) ^ (srow & 7);
    const int wg1 = (2 * (lane & 15) + 1) ^ (srow & 7);

    const unsigned short* ar[2];
#pragma unroll
    for (int m = 0; m < 2; ++m) {
        int r   = m0 + wid * 32 + m * 16 + fr;
        int tok = bucket[e * T_TOK + min(r, n_e - 1)] >> 1;
        ar[m] = xb + (size_t)tok * H_DIM + fq * 8;
    }

    f32x4 accg[2] = {};
    f32x4 accu[2] = {};

    {
        float4 g0 = *(const float4*)(gsrc + 0),  g1 = *(const float4*)(gsrc + 4);
        float4 g2 = *(const float4*)(gsrc + 8),  g3 = *(const float4*)(gsrc + 12);
        float4 u0 = *(const float4*)(usrc + 0),  u1 = *(const float4*)(usrc + 4);
        float4 u2 = *(const float4*)(usrc + 8),  u3 = *(const float4*)(usrc + 12);
        *(short8*)&sG[0][srow * 256 + wg0 * 8] = cvt8(g0, g1);
        *(short8*)&sG[0][srow * 256 + wg1 * 8] = cvt8(g2, g3);
        *(short8*)&sU[0][srow * 256 + wg0 * 8] = cvt8(u0, u1);
        *(short8*)&sU[0][srow * 256 + wg1 * 8] = cvt8(u2, u3);
    }
    __syncthreads();

    for (int t = 0; t < 8; ++t) {
        const int kb      = t * 256;
        const int kb_next = min(t + 1, 7) * 256;

        short8 a[8][2];
#pragma unroll
        for (int kk = 0; kk < 8; ++kk)
#pragma unroll
            for (int m = 0; m < 2; ++m)
                a[kk][m] = *(const short8*)(ar[m] + kb + kk * 32);

        float4 g0 = *(const float4*)(gsrc + kb_next + 0);
        float4 g1 = *(const float4*)(gsrc + kb_next + 4);
        float4 g2 = *(const float4*)(gsrc + kb_next + 8);
        float4 g3 = *(const float4*)(gsrc + kb_next + 12);
        float4 u0 = *(const float4*)(usrc + kb_next + 0);
        float4 u1 = *(const float4*)(usrc + kb_next + 4);
        float4 u2 = *(const float4*)(usrc + kb_next + 8);
        float4 u3 = *(const float4*)(usrc + kb_next + 12);

        const unsigned short* G = sG[t & 1];
        const unsigned short* U = sU[t & 1];
#pragma unroll
        for (int kk = 0; kk < 8; ++kk) {
            int slot = (kk * 4 + fq) ^ (fr & 7);
            short8 bg = *(const short8*)&G[fr * 256 + slot * 8];
            short8 bu = *(const short8*)&U[fr * 256 + slot * 8];
#pragma unroll
            for (int m = 0; m < 2; ++m) {
                accg[m] = __builtin_amdgcn_mfma_f32_16x16x32_bf16(a[kk][m], bg, accg[m], 0, 0, 0);
                accu[m] = __builtin_amdgcn_mfma_f32_16x16x32_bf16(a[kk][m], bu, accu[m], 0, 0, 0);
            }
        }

        unsigned short* Gw = (unsigned short*)sG[(t + 1) & 1];
        unsigned short* Uw = (unsigned short*)sU[(t + 1) & 1];
        *(short8*)&Gw[srow * 256 + wg0 * 8] = cvt8(g0, g1);
        *(short8*)&Gw[srow * 256 + wg1 * 8] = cvt8(g2, g3);
        *(short8*)&Uw[srow * 256 + wg0 * 8] = cvt8(u0, u1);
        *(short8*)&Uw[srow * 256 + wg1 * 8] = cvt8(u2, u3);
        __syncthreads();
    }

#pragma unroll
    for (int m = 0; m < 2; ++m) {
#pragma unroll
        for (int j = 0; j < 4; ++j) {
            int r = m0 + wid * 32 + m * 16 + fq * 4 + j;
            if (r < n_e) {
                int pid = bucket[e * T_TOK + r];
                float g = accg[m][j];
                float u = accu[m][j];
                float sg = g / (1.f + expf(-g));
                *(unsigned short*)(act + (size_t)pid * I_DIM + n0 + fr) = f2bf(sg * u);
            }
        }
    }
}

extern "C" void kernel_launch(void* const* d_in, const int* in_sizes, int n_in,
                              void* d_out, int out_size, void* d_ws, size_t ws_size,
                              hipStream_t stream) {
    const float* x      = (const float*)d_in[0];
    const float* logits = (const float*)d_in[1];
    const float* w13    = (const float*)d_in[2];
    const float* w2     = (const float*)d_in[3];
    float* out = (float*)d_out;

    char* ws = (char*)d_ws;
    // disjoint layout (bytes):
    int*   count  = (int*)(ws + 0);                         // 256 B
    int*   bucket = (int*)(ws + 256);                       // 16 KB -> 16640
    float* pair_w = (float*)(ws + 16640);                   // 4 KB  -> 20736
    unsigned short* xb  = (unsigned short*)(ws + 24576);    // 2 MB  -> 2,121,728
    __hip_bfloat16* act = (__hip_bfloat16*)(ws + 2121728);  // 2 MB  -> 4,218,880
    const size_t O_W13B = 4218880;
    unsigned short* w13b = (unsigned short*)(ws + O_W13B);  // 64 MB -> 71,327,744
    float* ybuf_big = (float*)(ws + 71327744);              // 8 MB  -> 79,716,352
    float* ybuf_fb  = (float*)(ws + O_W13B);                // fallback: 8 MB at w13b slot
    const size_t NEED = 79716352;

    xcvt_kernel<<<(T_TOK * H_DIM / 8) / 256, 256, 0, stream>>>(x, xb);
    routing_kernel<<<1, 512, 0, stream>>>(logits, count, bucket, pair_w);

    if (ws_size >= NEED) {
        conv13_kernel<<<((size_t)E_NUM * 2 * I_DIM * H_DIM / 8) / 256, 256, 0, stream>>>(w13, w13b);
        gemm1_silu_kernel<<<dim3(I_DIM / 32, 4, E_NUM), 256, 0, stream>>>(
            xb, w13b, count, bucket, act);
        gemm2_kernel<<<dim3(H_DIM / 32, 4, E_NUM), 256, 0, stream>>>(
            act, w2, count, bucket, ybuf_big);
        combine_kernel<<<(T_TOK * (H_DIM / 4)) / 256, 256, 0, stream>>>(ybuf_big, pair_w, out);
    } else {
        gemm1_fb_kernel<<<dim3(I_DIM / 16, 4, E_NUM), 256, 0, stream>>>(
            xb, w13, count, bucket, act);
        gemm2_kernel<<<dim3(H_DIM / 32, 4, E_NUM), 256, 0, stream>>>(
            act, w2, count, bucket, ybuf_fb);
        combine_kernel<<<(T_TOK * (H_DIM / 4)) / 256, 256, 0, stream>>>(ybuf_fb, pair_w, out);
    }
}